// Round 1
// baseline (9720.161 us; speedup 1.0000x reference)
//
#include <hip/hip_runtime.h>
#include <stdint.h>

// Persistent-kernel LSTM, MI355X.
//   - embW[v][col] = emb[v]·W_ih[col] + b_ih[col] + b_hh[col]  (precomputed: input GEMM == gather)
//   - 256 WGs: 4 independent batch-groups (16 samples) × 64 WGs (16 hidden each, all 4 gates)
//   - W_hh slice resident in VGPRs as bf16 MFMA B-fragments (128 VGPR/lane)
//   - per-step sync: per-WG monotonic flags + double-buffered bf16 h, all agent-scope atomics
//     (cache-bypassing => coherent across XCDs without fences)
// ws layout: [0,1KB) flags | [4096, +256KB) h double buffer | [0x50000, +4MB) embW fp32

#define T_STEPS 1024
#define BATCH   64
#define EDIM    256
#define HDIM    1024

typedef float f32x4  __attribute__((ext_vector_type(4)));
typedef short bf16x8 __attribute__((ext_vector_type(8)));

__device__ __forceinline__ unsigned short f2bf(float f) {
  union { float f; uint32_t u; } v; v.f = f;
  uint32_t r = (v.u + 0x7FFFu + ((v.u >> 16) & 1u)) >> 16;  // RNE
  return (unsigned short)r;
}
__device__ __forceinline__ float sigf(float x) { return 1.f / (1.f + __expf(-x)); }
__device__ __forceinline__ float tanh_fast(float x) {
  float ax = fabsf(x);
  float e  = __expf(-2.f * ax);
  float t  = (1.f - e) / (1.f + e);
  return copysignf(t, x);
}

__global__ void __launch_bounds__(256)
embw_kernel(const float* __restrict__ emb, const float* __restrict__ W_ih,
            const float* __restrict__ b_ih, const float* __restrict__ b_hh,
            float* __restrict__ embW)
{
  __shared__ float ev[EDIM];
  const int v   = blockIdx.y;
  const int col = blockIdx.x * 256 + threadIdx.x;
  ev[threadIdx.x] = emb[v * EDIM + threadIdx.x];
  __syncthreads();
  const float4* wr = (const float4*)(W_ih + (size_t)col * EDIM);
  float acc = b_ih[col] + b_hh[col];
#pragma unroll 4
  for (int e4 = 0; e4 < EDIM / 4; ++e4) {
    const float4 q = wr[e4];
    acc += ev[4*e4+0] * q.x + ev[4*e4+1] * q.y + ev[4*e4+2] * q.z + ev[4*e4+3] * q.w;
  }
  embW[(size_t)v * (4 * HDIM) + col] = acc;
}

__global__ void __launch_bounds__(256, 1)
lstm_kernel(const int* __restrict__ tokens, const int* __restrict__ seq_len,
            const float* __restrict__ W_hh, const float* __restrict__ embW,
            uint32_t* hbuf, uint32_t* flags, float* __restrict__ out)
{
  const int tid = threadIdx.x;
  const int bid = blockIdx.x;     // 0..255
  const int g   = bid & 3;        // batch group
  const int wig = bid >> 2;       // WG within group: hidden slice
  const int hb  = wig << 4;       // hidden base (16 per WG)
  const int gs0 = g << 4;         // sample base (16 per group)
  const int w   = tid >> 6;       // wave 0..3 (K-split: 256 each)
  const int l   = tid & 63;
  const int lr  = l & 15;         // MFMA m / n index
  const int lq  = l >> 4;         // MFMA k-quad

  // ---- stage W_hh slice into registers as bf16 B-fragments: B[k][n]=W_hh[n_row][k] ----
  bf16x8 bfrag[4][8];             // [gate][kstep]
#pragma unroll
  for (int n = 0; n < 4; ++n) {
    const float* wrow = W_hh + (size_t)(n * HDIM + hb + lr) * HDIM + w * 256 + lq * 8;
#pragma unroll
    for (int ks = 0; ks < 8; ++ks) {
      union { bf16x8 v; unsigned short u[8]; } bu;
#pragma unroll
      for (int e = 0; e < 8; ++e) bu.u[e] = f2bf(wrow[ks * 32 + e]);
      bfrag[n][ks] = bu.v;
    }
  }

  const int s  = tid >> 4;        // pointwise: sample-local
  const int j  = tid & 15;        // pointwise: hidden-local
  const int b  = gs0 + s;
  const int sl = seq_len[b];
  float c = 0.f, lastc = 0.f;

  __shared__ float part[4][4][16][16];   // [wave][gate][m][n]

  uint32_t* gflags = flags + g * 64;

  for (int t = 0; t < T_STEPS; ++t) {
    // input-gate contribution: independent of the barrier -> prefetch early
    const int tok = tokens[t * BATCH + b];
    const float* er = embW + (size_t)tok * (4 * HDIM) + hb + j;
    float gi = er[0], gf = er[HDIM], gg = er[2 * HDIM], go = er[3 * HDIM];

    if (t > 0) {
      const uint32_t* hrow = hbuf + ((t - 1) & 1) * (BATCH * HDIM / 2)
                           + (gs0 + lr) * (HDIM / 2) + ((w * 256 + lq * 8) >> 1);
      uint32_t areg[8][4];
      // issue ALL A loads before any MFMA: one L3 latency per step, not eight
#pragma unroll
      for (int ks = 0; ks < 8; ++ks)
#pragma unroll
        for (int d = 0; d < 4; ++d)
          areg[ks][d] = __hip_atomic_load(hrow + ks * 16 + d,
                                          __ATOMIC_RELAXED, __HIP_MEMORY_SCOPE_AGENT);
      f32x4 a0 = {0.f,0.f,0.f,0.f}, a1 = a0, a2 = a0, a3 = a0;
#pragma unroll
      for (int ks = 0; ks < 8; ++ks) {
        union { bf16x8 v; uint32_t u[4]; } au;
        au.u[0] = areg[ks][0]; au.u[1] = areg[ks][1];
        au.u[2] = areg[ks][2]; au.u[3] = areg[ks][3];
        a0 = __builtin_amdgcn_mfma_f32_16x16x32_bf16(au.v, bfrag[0][ks], a0, 0, 0, 0);
        a1 = __builtin_amdgcn_mfma_f32_16x16x32_bf16(au.v, bfrag[1][ks], a1, 0, 0, 0);
        a2 = __builtin_amdgcn_mfma_f32_16x16x32_bf16(au.v, bfrag[2][ks], a2, 0, 0, 0);
        a3 = __builtin_amdgcn_mfma_f32_16x16x32_bf16(au.v, bfrag[3][ks], a3, 0, 0, 0);
      }
#pragma unroll
      for (int r = 0; r < 4; ++r) {        // C layout: col=lane&15, row=(lane>>4)*4+reg
        const int m = lq * 4 + r;
        part[w][0][m][lr] = a0[r];
        part[w][1][m][lr] = a1[r];
        part[w][2][m][lr] = a2[r];
        part[w][3][m][lr] = a3[r];
      }
    }
    __syncthreads();

    if (t > 0) {
#pragma unroll
      for (int ww = 0; ww < 4; ++ww) {
        gi += part[ww][0][s][j];
        gf += part[ww][1][s][j];
        gg += part[ww][2][s][j];
        go += part[ww][3][s][j];
      }
    }

    const float cn = sigf(gf) * c + sigf(gi) * tanh_fast(gg);
    const float hn = sigf(go) * tanh_fast(cn);
    c = cn;
    if ((t == 0) || (t < sl)) lastc = cn;   // freeze mask (step 0 always valid)

    // h -> bf16 pair -> agent-scope store (coherence point; no fences needed)
    const unsigned short hu = f2bf(hn);
    const int other = __shfl_xor((int)hu, 1);
    if ((j & 1) == 0) {
      const uint32_t pk = (uint32_t)hu | ((uint32_t)(unsigned short)other << 16);
      __hip_atomic_store(hbuf + (t & 1) * (BATCH * HDIM / 2) + b * (HDIM / 2) + ((hb + j) >> 1),
                         pk, __ATOMIC_RELAXED, __HIP_MEMORY_SCOPE_AGENT);
    }
    __syncthreads();   // barrier drains vmcnt: all h stores acked at coherence point

    if (t + 1 < T_STEPS) {
      if (tid == 0)
        __hip_atomic_store(gflags + wig, (uint32_t)(t + 1),
                           __ATOMIC_RELEASE, __HIP_MEMORY_SCOPE_AGENT);
      if (w == 0) {      // wave 0 polls this group's 64 flags, one lane each
        uint32_t v;
        do {
          v = __hip_atomic_load(gflags + l, __ATOMIC_RELAXED, __HIP_MEMORY_SCOPE_AGENT);
        } while (!__all((int)(v > (uint32_t)t)));
      }
      __syncthreads();
    }
  }

  out[(size_t)b * HDIM + hb + j] = lastc;
}

extern "C" void kernel_launch(void* const* d_in, const int* in_sizes, int n_in,
                              void* d_out, int out_size, void* d_ws, size_t ws_size,
                              hipStream_t stream) {
  const int*   tokens = (const int*)d_in[0];
  const int*   seqlen = (const int*)d_in[1];
  const float* emb    = (const float*)d_in[2];
  const float* W_ih   = (const float*)d_in[3];
  const float* W_hh   = (const float*)d_in[4];
  const float* b_ih   = (const float*)d_in[5];
  const float* b_hh   = (const float*)d_in[6];
  float* out = (float*)d_out;

  uint8_t*  ws    = (uint8_t*)d_ws;
  uint32_t* flags = (uint32_t*)ws;                  // 256 * 4 B
  uint32_t* hbuf  = (uint32_t*)(ws + 4096);         // 2 * 64*1024 bf16 = 256 KB
  float*    embW  = (float*)(ws + 0x50000);         // 256 * 4096 fp32 = 4 MB

  hipMemsetAsync(flags, 0, 1024, stream);           // barrier state must be zeroed every launch
  embw_kernel<<<dim3(16, 256), 256, 0, stream>>>(emb, W_ih, b_ih, b_hh, embW);
  lstm_kernel<<<dim3(256), 256, 0, stream>>>(tokens, seqlen, W_hh, embW, hbuf, flags, out);
}

// Round 2
// 7263.197 us; speedup vs baseline: 1.3383x; 1.3383x over previous
//
#include <hip/hip_runtime.h>
#include <stdint.h>

// Persistent-kernel LSTM, MI355X.
//   - embW[v][col] = emb[v]·W_ih[col] + b_ih[col] + b_hh[col]  (precomputed: input GEMM == gather)
//   - 256 WGs: 4 independent batch-groups (16 samples) × 64 WGs (16 hidden each, all 4 gates)
//   - W_hh slice resident in VGPRs/AGPRs as bf16 MFMA B-fragments (128 regs/lane)
//   - per-step sync: per-WG monotonic flags + double-buffered bf16 h, agent-scope / cache-bypass
//   - R1 change: h-fragment loads are ONE asm block of 8x global_load_dwordx4 sc0 sc1
//     (pipelined, single L3 latency) instead of 32 serialized atomic dword loads.
// ws layout: [0,1KB) flags | [4096, +256KB) h double buffer | [0x50000, +4MB) embW fp32

#define T_STEPS 1024
#define BATCH   64
#define EDIM    256
#define HDIM    1024

typedef float    f32x4  __attribute__((ext_vector_type(4)));
typedef short    bf16x8 __attribute__((ext_vector_type(8)));
typedef uint32_t u32x4  __attribute__((ext_vector_type(4)));

__device__ __forceinline__ unsigned short f2bf(float f) {
  union { float f; uint32_t u; } v; v.f = f;
  uint32_t r = (v.u + 0x7FFFu + ((v.u >> 16) & 1u)) >> 16;  // RNE
  return (unsigned short)r;
}
__device__ __forceinline__ float sigf(float x) { return 1.f / (1.f + __expf(-x)); }
__device__ __forceinline__ float tanh_fast(float x) {
  float ax = fabsf(x);
  float e  = __expf(-2.f * ax);
  float t  = (1.f - e) / (1.f + e);
  return copysignf(t, x);
}

__global__ void __launch_bounds__(256)
embw_kernel(const float* __restrict__ emb, const float* __restrict__ W_ih,
            const float* __restrict__ b_ih, const float* __restrict__ b_hh,
            float* __restrict__ embW)
{
  __shared__ float ev[EDIM];
  const int v   = blockIdx.y;
  const int col = blockIdx.x * 256 + threadIdx.x;
  ev[threadIdx.x] = emb[v * EDIM + threadIdx.x];
  __syncthreads();
  const float4* wr = (const float4*)(W_ih + (size_t)col * EDIM);
  float acc = b_ih[col] + b_hh[col];
#pragma unroll 4
  for (int e4 = 0; e4 < EDIM / 4; ++e4) {
    const float4 q = wr[e4];
    acc += ev[4*e4+0] * q.x + ev[4*e4+1] * q.y + ev[4*e4+2] * q.z + ev[4*e4+3] * q.w;
  }
  embW[(size_t)v * (4 * HDIM) + col] = acc;
}

__global__ void __launch_bounds__(256, 1)
lstm_kernel(const int* __restrict__ tokens, const int* __restrict__ seq_len,
            const float* __restrict__ W_hh, const float* __restrict__ embW,
            uint32_t* hbuf, uint32_t* flags, float* __restrict__ out)
{
  const int tid = threadIdx.x;
  const int bid = blockIdx.x;     // 0..255
  const int g   = bid & 3;        // batch group
  const int wig = bid >> 2;       // WG within group: hidden slice
  const int hb  = wig << 4;       // hidden base (16 per WG)
  const int gs0 = g << 4;         // sample base (16 per group)
  const int w   = tid >> 6;       // wave 0..3 (K-split: 256 each)
  const int l   = tid & 63;
  const int lr  = l & 15;         // MFMA m / n index
  const int lq  = l >> 4;         // MFMA k-quad

  // ---- stage W_hh slice into registers as bf16 B-fragments: B[k][n]=W_hh[n_row][k] ----
  bf16x8 bfrag[4][8];             // [gate][kstep]
#pragma unroll
  for (int n = 0; n < 4; ++n) {
    const float* wrow = W_hh + (size_t)(n * HDIM + hb + lr) * HDIM + w * 256 + lq * 8;
#pragma unroll
    for (int ks = 0; ks < 8; ++ks) {
      union { bf16x8 v; unsigned short u[8]; } bu;
#pragma unroll
      for (int e = 0; e < 8; ++e) bu.u[e] = f2bf(wrow[ks * 32 + e]);
      bfrag[n][ks] = bu.v;
    }
  }

  const int s  = tid >> 4;        // pointwise: sample-local
  const int j  = tid & 15;        // pointwise: hidden-local
  const int b  = gs0 + s;
  const int sl = seq_len[b];
  float c = 0.f, lastc = 0.f;

  __shared__ float part[4][4][16][16];   // [wave][gate][m][n]

  uint32_t* gflags = flags + g * 64;

  // per-lane byte offset of this lane's A-fragment row within one h buffer
  const uint32_t voff_base = (uint32_t)((gs0 + lr) * (HDIM * 2) + (w * 512 + lq * 16));

  for (int t = 0; t < T_STEPS; ++t) {
    // input-gate contribution: independent of the barrier -> prefetch early
    const int tok = tokens[t * BATCH + b];
    const float* er = embW + (size_t)tok * (4 * HDIM) + hb + j;
    float gi = er[0], gf = er[HDIM], gg = er[2 * HDIM], go = er[3 * HDIM];

    if (t > 0) {
      const uint32_t voff = ((uint32_t)((t - 1) & 1)) * (BATCH * HDIM * 2) + voff_base;
      u32x4 r0, r1, r2, r3, r4, r5, r6, r7;
      // 8 pipelined cache-bypassing 16B loads + single drain, all in ONE asm block
      asm volatile(
        "global_load_dwordx4 %0, %8, %9 sc0 sc1\n\t"
        "global_load_dwordx4 %1, %8, %9 offset:64 sc0 sc1\n\t"
        "global_load_dwordx4 %2, %8, %9 offset:128 sc0 sc1\n\t"
        "global_load_dwordx4 %3, %8, %9 offset:192 sc0 sc1\n\t"
        "global_load_dwordx4 %4, %8, %9 offset:256 sc0 sc1\n\t"
        "global_load_dwordx4 %5, %8, %9 offset:320 sc0 sc1\n\t"
        "global_load_dwordx4 %6, %8, %9 offset:384 sc0 sc1\n\t"
        "global_load_dwordx4 %7, %8, %9 offset:448 sc0 sc1\n\t"
        "s_waitcnt vmcnt(0)"
        : "=&v"(r0), "=&v"(r1), "=&v"(r2), "=&v"(r3),
          "=&v"(r4), "=&v"(r5), "=&v"(r6), "=&v"(r7)
        : "v"(voff), "s"(hbuf)
        : "memory");

      u32x4 areg[8] = {r0, r1, r2, r3, r4, r5, r6, r7};
      f32x4 a0 = {0.f,0.f,0.f,0.f}, a1 = a0, a2 = a0, a3 = a0;
#pragma unroll
      for (int ks = 0; ks < 8; ++ks) {
        union { bf16x8 v; u32x4 u; } au;
        au.u = areg[ks];
        a0 = __builtin_amdgcn_mfma_f32_16x16x32_bf16(au.v, bfrag[0][ks], a0, 0, 0, 0);
        a1 = __builtin_amdgcn_mfma_f32_16x16x32_bf16(au.v, bfrag[1][ks], a1, 0, 0, 0);
        a2 = __builtin_amdgcn_mfma_f32_16x16x32_bf16(au.v, bfrag[2][ks], a2, 0, 0, 0);
        a3 = __builtin_amdgcn_mfma_f32_16x16x32_bf16(au.v, bfrag[3][ks], a3, 0, 0, 0);
      }
#pragma unroll
      for (int r = 0; r < 4; ++r) {        // C layout: col=lane&15, row=(lane>>4)*4+reg
        const int m = lq * 4 + r;
        part[w][0][m][lr] = a0[r];
        part[w][1][m][lr] = a1[r];
        part[w][2][m][lr] = a2[r];
        part[w][3][m][lr] = a3[r];
      }
    }
    __syncthreads();

    if (t > 0) {
#pragma unroll
      for (int ww = 0; ww < 4; ++ww) {
        gi += part[ww][0][s][j];
        gf += part[ww][1][s][j];
        gg += part[ww][2][s][j];
        go += part[ww][3][s][j];
      }
    }

    const float cn = sigf(gf) * c + sigf(gi) * tanh_fast(gg);
    const float hn = sigf(go) * tanh_fast(cn);
    c = cn;
    if ((t == 0) || (t < sl)) lastc = cn;   // freeze mask (step 0 always valid)

    // h -> bf16 pair -> agent-scope store (write-through to coherence point)
    const unsigned short hu = f2bf(hn);
    const int other = __shfl_xor((int)hu, 1);
    if ((j & 1) == 0) {
      const uint32_t pk = (uint32_t)hu | ((uint32_t)(unsigned short)other << 16);
      __hip_atomic_store(hbuf + (t & 1) * (BATCH * HDIM / 2) + b * (HDIM / 2) + ((hb + j) >> 1),
                         pk, __ATOMIC_RELAXED, __HIP_MEMORY_SCOPE_AGENT);
    }
    __syncthreads();   // barrier drains vmcnt: all h stores acked at coherence point

    if (t + 1 < T_STEPS) {
      if (tid == 0)
        __hip_atomic_store(gflags + wig, (uint32_t)(t + 1),
                           __ATOMIC_RELEASE, __HIP_MEMORY_SCOPE_AGENT);
      if (w == 0) {      // wave 0 polls this group's 64 flags, one lane each
        while (true) {
          uint32_t v = __hip_atomic_load(gflags + l, __ATOMIC_RELAXED, __HIP_MEMORY_SCOPE_AGENT);
          if (__all((int)(v > (uint32_t)t))) break;
          __builtin_amdgcn_s_sleep(1);   // backoff: reduce L3 same-line hammering
        }
      }
      __syncthreads();
    }
  }

  out[(size_t)b * HDIM + hb + j] = lastc;
}

extern "C" void kernel_launch(void* const* d_in, const int* in_sizes, int n_in,
                              void* d_out, int out_size, void* d_ws, size_t ws_size,
                              hipStream_t stream) {
  const int*   tokens = (const int*)d_in[0];
  const int*   seqlen = (const int*)d_in[1];
  const float* emb    = (const float*)d_in[2];
  const float* W_ih   = (const float*)d_in[3];
  const float* W_hh   = (const float*)d_in[4];
  const float* b_ih   = (const float*)d_in[5];
  const float* b_hh   = (const float*)d_in[6];
  float* out = (float*)d_out;

  uint8_t*  ws    = (uint8_t*)d_ws;
  uint32_t* flags = (uint32_t*)ws;                  // 256 * 4 B
  uint32_t* hbuf  = (uint32_t*)(ws + 4096);         // 2 * 64*1024 bf16 = 256 KB
  float*    embW  = (float*)(ws + 0x50000);         // 256 * 4096 fp32 = 4 MB

  hipMemsetAsync(flags, 0, 1024, stream);           // barrier state must be zeroed every launch
  embw_kernel<<<dim3(16, 256), 256, 0, stream>>>(emb, W_ih, b_ih, b_hh, embW);
  lstm_kernel<<<dim3(256), 256, 0, stream>>>(tokens, seqlen, W_hh, embW, hbuf, flags, out);
}

// Round 5
// 4101.455 us; speedup vs baseline: 2.3699x; 1.7709x over previous
//
#include <hip/hip_runtime.h>
#include <stdint.h>

// Persistent-kernel LSTM, MI355X — R5: R2 skeleton + central counter barrier.
//   - embW[v][col] = emb[v]·W_ih[col] + b_ih[col] + b_hh[col]  (input GEMM == gather)
//   - 256 WGs: 4 independent batch-groups (16 samples) × 64 WGs (16 hidden each, all 4 gates)
//   - W_hh slice resident in VGPRs as bf16 MFMA B-fragments (128 regs/lane)
//   - h exchange: double-buffered bf16, sc0 sc1 stores/loads (memory-side coherence point)
//   - R5 sync: per-group cumulative arrival counter (atomicAdd, fire-and-forget) +
//     single-dword wave poll (all lanes same addr -> 1 coalesced request, no sleep).
//     Replaces 64-flag array: kills poll contention + sleep quantization.
//   - LDS partial tile padded to stride 17 (R2: 3.35e7 conflict cycles).
// ws layout: [0,4KB) cnt[4] (64B apart) | [4096, +256KB) h dbuf | [0x50000, +4MB) embW fp32

#define T_STEPS 1024
#define BATCH   64
#define EDIM    256
#define HDIM    1024

typedef float    f32x4  __attribute__((ext_vector_type(4)));
typedef short    bf16x8 __attribute__((ext_vector_type(8)));
typedef uint32_t u32x4  __attribute__((ext_vector_type(4)));

__device__ __forceinline__ unsigned short f2bf(float f) {
  union { float f; uint32_t u; } v; v.f = f;
  uint32_t r = (v.u + 0x7FFFu + ((v.u >> 16) & 1u)) >> 16;  // RNE
  return (unsigned short)r;
}
__device__ __forceinline__ float sigf(float x) { return 1.f / (1.f + __expf(-x)); }
__device__ __forceinline__ float tanh_fast(float x) {
  float ax = fabsf(x);
  float e  = __expf(-2.f * ax);
  float t  = (1.f - e) / (1.f + e);
  return copysignf(t, x);
}

__global__ void __launch_bounds__(256)
embw_kernel(const float* __restrict__ emb, const float* __restrict__ W_ih,
            const float* __restrict__ b_ih, const float* __restrict__ b_hh,
            float* __restrict__ embW)
{
  __shared__ float ev[EDIM];
  const int v   = blockIdx.y;
  const int col = blockIdx.x * 256 + threadIdx.x;
  ev[threadIdx.x] = emb[v * EDIM + threadIdx.x];
  __syncthreads();
  const float4* wr = (const float4*)(W_ih + (size_t)col * EDIM);
  float acc = b_ih[col] + b_hh[col];
#pragma unroll 4
  for (int e4 = 0; e4 < EDIM / 4; ++e4) {
    const float4 q = wr[e4];
    acc += ev[4*e4+0] * q.x + ev[4*e4+1] * q.y + ev[4*e4+2] * q.z + ev[4*e4+3] * q.w;
  }
  embW[(size_t)v * (4 * HDIM) + col] = acc;
}

__global__ void __launch_bounds__(256, 1)
lstm_kernel(const int* __restrict__ tokens, const int* __restrict__ seq_len,
            const float* __restrict__ W_hh, const float* __restrict__ embW,
            uint32_t* hbuf, uint32_t* cnt, float* __restrict__ out)
{
  const int tid = threadIdx.x;
  const int bid = blockIdx.x;     // 0..255
  const int g   = bid & 3;        // batch group
  const int wig = bid >> 2;       // WG within group: hidden slice
  const int hb  = wig << 4;       // hidden base (16 per WG)
  const int gs0 = g << 4;         // sample base (16 per group)
  const int w   = tid >> 6;       // wave 0..3 (K-split: 256 each)
  const int l   = tid & 63;
  const int lr  = l & 15;         // MFMA m / n index
  const int lq  = l >> 4;         // MFMA k-quad

  // ---- stage W_hh slice into registers as bf16 MFMA B-fragments ----
  bf16x8 bfrag[4][8];             // [gate][kstep]
#pragma unroll
  for (int n = 0; n < 4; ++n) {
    const float* wrow = W_hh + (size_t)(n * HDIM + hb + lr) * HDIM + w * 256 + lq * 8;
#pragma unroll
    for (int ks = 0; ks < 8; ++ks) {
      union { bf16x8 v; unsigned short u[8]; } bu;
#pragma unroll
      for (int e = 0; e < 8; ++e) bu.u[e] = f2bf(wrow[ks * 32 + e]);
      bfrag[n][ks] = bu.v;
    }
  }

  const int s  = tid >> 4;        // pointwise: sample-local
  const int j  = tid & 15;        // pointwise: hidden-local
  const int b  = gs0 + s;
  const int sl = seq_len[b];
  float c = 0.f, lastc = 0.f;

  __shared__ float part[4][4][16][17];   // [wave][gate][m][n] pad 17: no 4-way conflicts

  uint32_t* cnt_g = cnt + g * 16;        // 64B-separated per-group counter line

  const uint32_t voff_base = (uint32_t)((gs0 + lr) * (HDIM * 2) + (w * 512 + lq * 16));

  for (int t = 0; t < T_STEPS; ++t) {
    // embW gather — independent of the barrier, overlaps poll/detect latency
    const int tok = tokens[t * BATCH + b];
    const float* er = embW + (size_t)tok * (4 * HDIM) + hb + j;
    float gi = er[0], gf = er[HDIM], gg = er[2 * HDIM], go = er[3 * HDIM];

    if (t > 0) {
      const uint32_t voff = ((uint32_t)((t - 1) & 1)) * (BATCH * HDIM * 2) + voff_base;
      u32x4 r0, r1, r2, r3, r4, r5, r6, r7;
      // 8 pipelined cache-bypassing 16B loads + single drain (proven R2 path)
      asm volatile(
        "global_load_dwordx4 %0, %8, %9 sc0 sc1\n\t"
        "global_load_dwordx4 %1, %8, %9 offset:64 sc0 sc1\n\t"
        "global_load_dwordx4 %2, %8, %9 offset:128 sc0 sc1\n\t"
        "global_load_dwordx4 %3, %8, %9 offset:192 sc0 sc1\n\t"
        "global_load_dwordx4 %4, %8, %9 offset:256 sc0 sc1\n\t"
        "global_load_dwordx4 %5, %8, %9 offset:320 sc0 sc1\n\t"
        "global_load_dwordx4 %6, %8, %9 offset:384 sc0 sc1\n\t"
        "global_load_dwordx4 %7, %8, %9 offset:448 sc0 sc1\n\t"
        "s_waitcnt vmcnt(0)"
        : "=&v"(r0), "=&v"(r1), "=&v"(r2), "=&v"(r3),
          "=&v"(r4), "=&v"(r5), "=&v"(r6), "=&v"(r7)
        : "v"(voff), "s"(hbuf)
        : "memory");

      u32x4 areg[8] = {r0, r1, r2, r3, r4, r5, r6, r7};
      f32x4 a0 = {0.f,0.f,0.f,0.f}, a1 = a0, a2 = a0, a3 = a0;
#pragma unroll
      for (int ks = 0; ks < 8; ++ks) {
        union { bf16x8 v; u32x4 u; } au;
        au.u = areg[ks];
        a0 = __builtin_amdgcn_mfma_f32_16x16x32_bf16(au.v, bfrag[0][ks], a0, 0, 0, 0);
        a1 = __builtin_amdgcn_mfma_f32_16x16x32_bf16(au.v, bfrag[1][ks], a1, 0, 0, 0);
        a2 = __builtin_amdgcn_mfma_f32_16x16x32_bf16(au.v, bfrag[2][ks], a2, 0, 0, 0);
        a3 = __builtin_amdgcn_mfma_f32_16x16x32_bf16(au.v, bfrag[3][ks], a3, 0, 0, 0);
      }
#pragma unroll
      for (int r = 0; r < 4; ++r) {        // C layout: col=lane&15, row=(lane>>4)*4+reg
        const int m = lq * 4 + r;
        part[w][0][m][lr] = a0[r];
        part[w][1][m][lr] = a1[r];
        part[w][2][m][lr] = a2[r];
        part[w][3][m][lr] = a3[r];
      }
    }
    __syncthreads();

    if (t > 0) {
#pragma unroll
      for (int ww = 0; ww < 4; ++ww) {
        gi += part[ww][0][s][j];
        gf += part[ww][1][s][j];
        gg += part[ww][2][s][j];
        go += part[ww][3][s][j];
      }
    }

    const float cn = sigf(gf) * c + sigf(gi) * tanh_fast(gg);
    const float hn = sigf(go) * tanh_fast(cn);
    c = cn;
    if ((t == 0) || (t < sl)) lastc = cn;   // freeze mask (step 0 always valid)

    // h -> bf16 pair -> store to coherence point
    const unsigned short hu = f2bf(hn);
    const int other = __shfl_xor((int)hu, 1);
    if ((j & 1) == 0) {
      const uint32_t pk = (uint32_t)hu | ((uint32_t)(unsigned short)other << 16);
      __hip_atomic_store(hbuf + (t & 1) * (BATCH * HDIM / 2) + b * (HDIM / 2) + ((hb + j) >> 1),
                         pk, __ATOMIC_RELAXED, __HIP_MEMORY_SCOPE_AGENT);
    }
    asm volatile("s_waitcnt vmcnt(0)" ::: "memory");  // per-wave drain: h acked
    __syncthreads();                                  // => ALL waves' h acked

    if (t + 1 < T_STEPS) {
      // arrival: one fire-and-forget add per WG (result unused -> no wait on producer)
      if (tid == 0)
        __hip_atomic_fetch_add(cnt_g, 1u, __ATOMIC_RELAXED, __HIP_MEMORY_SCOPE_AGENT);
      if (w == 0) {
        // wave 0 polls ONE dword (all lanes same addr -> single coalesced request)
        const uint32_t target = (uint32_t)(64 * (t + 1));
        uint32_t fv;
        do {
          asm volatile("global_load_dword %0, %1, %2 sc0 sc1\n\ts_waitcnt vmcnt(0)"
                       : "=v"(fv) : "v"(0u), "s"(cnt_g) : "memory");
        } while (fv < target);
      }
      __syncthreads();
    }
  }

  out[(size_t)b * HDIM + hb + j] = lastc;
}

extern "C" void kernel_launch(void* const* d_in, const int* in_sizes, int n_in,
                              void* d_out, int out_size, void* d_ws, size_t ws_size,
                              hipStream_t stream) {
  const int*   tokens = (const int*)d_in[0];
  const int*   seqlen = (const int*)d_in[1];
  const float* emb    = (const float*)d_in[2];
  const float* W_ih   = (const float*)d_in[3];
  const float* W_hh   = (const float*)d_in[4];
  const float* b_ih   = (const float*)d_in[5];
  const float* b_hh   = (const float*)d_in[6];
  float* out = (float*)d_out;

  uint8_t*  ws    = (uint8_t*)d_ws;
  uint32_t* cnt   = (uint32_t*)ws;                  // 4 counters, 64B apart
  uint32_t* hbuf  = (uint32_t*)(ws + 4096);         // 2 * 64*1024 bf16 = 256 KB
  float*    embW  = (float*)(ws + 0x50000);         // 256 * 4096 fp32 = 4 MB

  hipMemsetAsync(ws, 0, 4096, stream);              // zero arrival counters every launch
  embw_kernel<<<dim3(16, 256), 256, 0, stream>>>(emb, W_ih, b_ih, b_hh, embW);
  lstm_kernel<<<dim3(256), 256, 0, stream>>>(tokens, seqlen, W_hh, embW, hbuf, cnt, out);
}